// Round 14
// baseline (151.980 us; speedup 1.0000x reference)
//
#include <hip/hip_runtime.h>
#include <hip/hip_fp16.h>

// EfficientAttention  B=4, S=4096, D=1024, fp32 in/out.
//   G[b] = x^T x (lower-tri 256^2 tiles, split-K=6, fp16 parts in d_out)
//   Gh = (1/32) sum parts (mirrored); Ph[b] = Wv Gh[b] (has the 1/32)
//   M = Wq^T Wk;  qw[b] = M xs[b];  kb = Wk^T bq;  qk = Wq^T bk
//   sv0 = bq.bk;  sv_b = kb.xs[b]   (reduce_tri extra block)
//   Rt[b] = Ph M^T + (1/32)(u2 ox qk + bv ox qw[b])
//   cv[b] = Ph kb + (1/32)(sv0 u2 + sv_b bv);  E[b] = x Rt^T + cv
// gemm8p: 8-phase 256x256, read-balanced 8/4/8/4 (B0[j+1] read at P4(j),
// covered by vmcnt(6) at end of P3 -- full load ledger in comments).

#define BATCH 4
#define SEQ   4096
#define DM    1024

typedef _Float16 h8 __attribute__((ext_vector_type(8)));
typedef _Float16 h4 __attribute__((ext_vector_type(4)));
typedef float    f4 __attribute__((ext_vector_type(4)));

__device__ inline void gload_lds16(const _Float16* g, _Float16* l) {
    __builtin_amdgcn_global_load_lds(
        (const __attribute__((address_space(1))) void*)g,
        (__attribute__((address_space(3))) void*)l,
        16, 0, 0);
}

__device__ inline int xcd_swz(int bid, int grid) {
    const int q = grid >> 3;
    return (bid & 7) * q + (bid >> 3);
}

__device__ inline float doth(const _Float16* wr, const float* v, int lane) {
    float s = 0.f;
    #pragma unroll
    for (int i = 0; i < 2; ++i) {
        const int k = i * 512 + lane * 8;
        h8 wv = *(const h8*)&wr[k];
        f4 v0 = *(const f4*)&v[k];
        f4 v1 = *(const f4*)&v[k + 4];
        s += (float)wv[0] * v0.x + (float)wv[1] * v0.y +
             (float)wv[2] * v0.z + (float)wv[3] * v0.w +
             (float)wv[4] * v1.x + (float)wv[5] * v1.y +
             (float)wv[6] * v1.z + (float)wv[7] * v1.w;
    }
    return s;
}
// weight row dotted against 4 xs vectors at once (reads wr once)
__device__ inline void doth4(const _Float16* wr, const float* xs, int lane, float* s) {
    #pragma unroll
    for (int i = 0; i < 2; ++i) {
        const int k = i * 512 + lane * 8;
        h8 wv = *(const h8*)&wr[k];
        #pragma unroll
        for (int b = 0; b < 4; ++b) {
            const float* v = xs + b * DM + k;
            f4 v0 = *(const f4*)&v[0];
            f4 v1 = *(const f4*)&v[4];
            s[b] += (float)wv[0] * v0.x + (float)wv[1] * v0.y +
                    (float)wv[2] * v0.z + (float)wv[3] * v0.w +
                    (float)wv[4] * v1.x + (float)wv[5] * v1.y +
                    (float)wv[6] * v1.z + (float)wv[7] * v1.w;
        }
    }
}
__device__ inline float dotf(const float* a, const float* b, int lane) {
    float s = 0.f;
    #pragma unroll
    for (int i = 0; i < 4; ++i) {
        const int k = i * 256 + lane * 4;
        f4 x = *(const f4*)&a[k];
        f4 y = *(const f4*)&b[k];
        s += x.x * y.x + x.y * y.y + x.z * y.z + x.w * y.w;
    }
    return s;
}
__device__ inline float wred(float s) {
    #pragma unroll
    for (int off = 32; off; off >>= 1) s += __shfl_down(s, off);
    return s;
}

// One launch: x batches (bid<4096: transpose+RM+colsum) and weights
// (bid>=4096: z=0 Wq->Wqt(T), z=1 Wk->Wkt(T), z=2 Wv->Wvh(RM)).
__global__ __launch_bounds__(256) void cvt_all(
    const float* __restrict__ x, const float* __restrict__ Wq,
    const float* __restrict__ Wk, const float* __restrict__ Wv,
    _Float16* __restrict__ xt, _Float16* __restrict__ xh,
    _Float16* __restrict__ Wqt, _Float16* __restrict__ Wkt,
    _Float16* __restrict__ Wvh, float* __restrict__ xs)
{
    __shared__ float tile[64][65];
    __shared__ float red[4][64];
    const int bid = blockIdx.x;
    const int t   = threadIdx.x;
    const int tr  = t >> 4;
    const int tc  = (t & 15) * 4;

    const float* src;
    _Float16 *dstT = nullptr, *dstRM = nullptr;
    int r0, c0, C, R;
    bool isX = bid < 4096;
    if (isX) {
        const int b  = bid >> 10;
        const int tt = bid & 1023;
        r0 = (tt >> 4) * 64; c0 = (tt & 15) * 64;
        R = SEQ; C = DM;
        src   = x  + (long)b * SEQ * DM;
        dstT  = xt + (long)b * SEQ * DM;
        dstRM = xh + (long)b * SEQ * DM;
        xs   += b * DM;
    } else {
        const int wb = bid - 4096;
        const int z  = wb >> 8;
        const int tt = wb & 255;
        r0 = (tt >> 4) * 64; c0 = (tt & 15) * 64;
        R = DM; C = DM;
        src = z == 0 ? Wq : (z == 1 ? Wk : Wv);
        if (z == 0) dstT = Wqt;
        else if (z == 1) dstT = Wkt;
        else dstRM = Wvh;
    }

    #pragma unroll
    for (int i = 0; i < 4; ++i) {
        const int r = tr + i * 16;
        f4 v = *(const f4*)&src[(long)(r0 + r) * C + c0 + tc];
        tile[r][tc + 0] = v.x; tile[r][tc + 1] = v.y;
        tile[r][tc + 2] = v.z; tile[r][tc + 3] = v.w;
        if (dstRM) {
            h4 h = { (_Float16)v.x, (_Float16)v.y, (_Float16)v.z, (_Float16)v.w };
            *(h4*)&dstRM[(long)(r0 + r) * C + c0 + tc] = h;
        }
    }
    __syncthreads();
    if (dstT) {
        #pragma unroll
        for (int i = 0; i < 4; ++i) {
            const int c = tr + i * 16;
            h4 h = { (_Float16)tile[tc + 0][c], (_Float16)tile[tc + 1][c],
                     (_Float16)tile[tc + 2][c], (_Float16)tile[tc + 3][c] };
            *(h4*)&dstT[(long)(c0 + c) * R + r0 + tc] = h;
        }
    }
    if (isX) {
        const int cc = t & 63;
        const int rb = (t >> 6) * 16;
        float ps = 0.f;
        #pragma unroll
        for (int r = 0; r < 16; ++r) ps += tile[rb + r][cc];
        red[t >> 6][cc] = ps;
        __syncthreads();
        if (t < 64)
            atomicAdd(&xs[c0 + t], red[0][t] + red[1][t] + red[2][t] + red[3][t]);
    }
}

// gw<1024:  e=gw: u2[b,e] = Wvh[e].xs[b] + S*bv[e]   (all 4 batches per wave)
// gw<2048:  qk[i] = Wqt[i].bk
// gw<3072:  kb[j] = Wkt[j].bq
__global__ __launch_bounds__(256) void gemv_misc(
    const _Float16* __restrict__ Wvh, const _Float16* __restrict__ Wqt,
    const _Float16* __restrict__ Wkt,
    const float* __restrict__ xs, const float* __restrict__ bv,
    const float* __restrict__ bk, const float* __restrict__ bq,
    float* __restrict__ u2, float* __restrict__ qk,
    float* __restrict__ kb)
{
    const int gw   = blockIdx.x * 4 + (threadIdx.x >> 6);
    const int lane = threadIdx.x & 63;
    if (gw < 1024) {
        float s[4] = {};
        doth4(Wvh + (long)gw * DM, xs, lane, s);
        #pragma unroll
        for (int b = 0; b < 4; ++b) {
            float r = wred(s[b]);
            if (lane == 0) u2[b * DM + gw] = r + (float)SEQ * bv[gw];
        }
    } else if (gw < 2048) {
        float s = wred(doth(Wqt + (long)(gw - 1024) * DM, bk, lane));
        if (lane == 0) qk[gw - 1024] = s;
    } else if (gw < 3072) {
        float s = wred(doth(Wkt + (long)(gw - 2048) * DM, bq, lane));
        if (lane == 0) kb[gw - 2048] = s;
    }
}

// gw<4096: cv[b,e] = Ph[b,e,:].kb + (sv0*u2 + sv_b*bv)/32
// gw<5120: i=gw-4096: qw[b,i] = Mh[i,:].xs[b]  (4 batches per wave)
__global__ __launch_bounds__(256) void gemv_cvqw(
    const _Float16* __restrict__ Ph, const _Float16* __restrict__ Mh,
    const float* __restrict__ kb, const float* __restrict__ xs,
    const float* __restrict__ u2, const float* __restrict__ bv,
    const float* __restrict__ sv,
    float* __restrict__ cv, float* __restrict__ qw)
{
    const int gw   = blockIdx.x * 4 + (threadIdx.x >> 6);
    const int lane = threadIdx.x & 63;
    if (gw < 4096) {
        const int b = gw >> 10;
        const int e = gw & 1023;
        float s = wred(doth(Ph + (long)b * DM * DM + (long)e * DM, kb, lane));
        if (lane == 0)
            cv[gw] = s + (sv[0] * u2[gw] + sv[1 + b] * bv[e]) * 0.03125f;
    } else if (gw < 5120) {
        const int i = gw - 4096;
        float s[4] = {};
        doth4(Mh + (long)i * DM, xs, lane, s);
        #pragma unroll
        for (int b = 0; b < 4; ++b) {
            float r = wred(s[b]);
            if (lane == 0) qw[b * DM + i] = r;
        }
    }
}

// Triangular reduce+mirror: Gh[b] from parts[job*6+s] (each 256x256 fp16).
// Block 640 (extra): sv[0] = bq.bk; sv[1+b] = kb.xs[b].
__global__ __launch_bounds__(256) void reduce_tri(
    const _Float16* __restrict__ parts, _Float16* __restrict__ Gh,
    const float* __restrict__ kb, const float* __restrict__ xs,
    const float* __restrict__ bq, const float* __restrict__ bk,
    float* __restrict__ sv)
{
    const int bid = blockIdx.x;
    if (bid == 640) {
        const int wv   = threadIdx.x >> 6;
        const int lane = threadIdx.x & 63;
        float s = wred(dotf(kb, xs + wv * DM, lane));
        if (lane == 0) sv[1 + wv] = s;
        if (wv == 0) {
            float s0 = wred(dotf(bq, bk, lane));
            if (lane == 0) sv[0] = s0;
        }
        return;
    }
    __shared__ _Float16 lds[64][72];
    const int job = bid >> 4;
    const int ch  = bid & 15;
    const int b   = job / 10;
    const int p   = job - b * 10;
    const int ti  = p >= 6 ? 3 : (p >= 3 ? 2 : (p >= 1 ? 1 : 0));
    const int tj  = p - ((ti * (ti + 1)) >> 1);
    const int li  = (ch >> 2) * 64;
    const int lj  = (ch & 3) * 64;
    const int t   = threadIdx.x;
    const int c8  = (t & 7) * 8;
    const long DD_ = (long)DM * DM;

    h8 o[2];
    #pragma unroll
    for (int h = 0; h < 2; ++h) {
        const int r = (t >> 3) + h * 32;
        float a[8] = {};
        #pragma unroll
        for (int s = 0; s < 6; ++s) {
            const _Float16* src = parts + ((long)(job * 6 + s) << 16);
            h8 v = *(const h8*)&src[(li + r) * 256 + lj + c8];
            #pragma unroll
            for (int j = 0; j < 8; ++j) a[j] += (float)v[j];
        }
        #pragma unroll
        for (int j = 0; j < 8; ++j) o[h][j] = (_Float16)(a[j] * 0.03125f);
        *(h8*)&Gh[b * DD_ + (long)(ti * 256 + li + r) * DM + tj * 256 + lj + c8] = o[h];
        *(h8*)&lds[r][c8] = o[h];
    }
    if (ti != tj) {
        __syncthreads();
        #pragma unroll
        for (int h = 0; h < 2; ++h) {
            const int r = (t >> 3) + h * 32;
            h8 m;
            #pragma unroll
            for (int j = 0; j < 8; ++j) m[j] = lds[c8 + j][r];
            *(h8*)&Gh[b * DD_ + (long)(tj * 256 + lj + r) * DM + ti * 256 + li + c8] = m;
        }
    }
}

// ---------------------------------------------------------------------------
// 8-phase 256x256 NT GEMM, read-balanced 8/4/8/4.
// Stage events (2 loads each): S(j,P1)=A1[j+1], S(j,P2)=B1[j+1],
//                              S(j,P3)=A0[j+2], S(j,P4)=B0[j+2].
// Read coverage: end-P4 vmcnt(4) -> landed through S(j,P2):
//   P1(j+1):A0[j+1]=S(j-1,P3) ok; P2:B1=S(j,P2) ok; P3:A1=S(j,P1) ok.
// P4(j) reads B0[j+1]=S(j-1,P4): covered by NEW vmcnt(6) at end of P3(j)
//   (leaves S(j,P1..P3) = 6 loads in flight). Tail: vmcnt(4) when P3's
//   stage skipped; full drain at j=NT-2's P4 as before.
// ---------------------------------------------------------------------------
template<typename OutT, int BIAS, int TRI>
__global__ __launch_bounds__(512, 1) void gemm8p(
    const _Float16* __restrict__ A, const _Float16* __restrict__ B,
    OutT* __restrict__ C,
    int K, int lda, int ldb, int ldc, int tilesX, int perZ,
    long aZ, long bZ, long cZ, int sk, long aK, long bK,
    const float* __restrict__ bc1, long bc1Z, float alpha)
{
    __shared__ _Float16 lds[2 * 32768];   // 128 KiB

    const int L = xcd_swz(blockIdx.x, gridDim.x);
    int tileM, tileN, cTileM, cTileN, NT;
    const float* pc1 = nullptr;
    if (TRI) {
        const int job = L / 6;
        const int s   = L - job * 6;
        const int b   = job / 10;
        const int p   = job - b * 10;
        const int ti  = p >= 6 ? 3 : (p >= 3 ? 2 : (p >= 1 ? 1 : 0));
        const int tj  = p - ((ti * (ti + 1)) >> 1);
        const int kOff = s < 4 ? s * 704 : 2816 + (s - 4) * 640;
        NT = s < 4 ? 11 : 10;
        A += (long)b * aZ + kOff;
        B += (long)b * aZ + kOff;
        C += (long)(job * 6 + s) * cZ;
        tileM = ti * 256; tileN = tj * 256;
        cTileM = 0; cTileN = 0;
    } else {
        const int z  = L / perZ;
        const int r0 = L - z * perZ;
        const int zb = z / sk;
        const int zk = z - zb * sk;
        A += (long)zb * aZ + (long)zk * aK;
        B += (long)zb * bZ + (long)zk * bK;
        C += (long)z * cZ;
        if (BIAS == 1) pc1 = bc1 + (long)zb * bc1Z;
        tileM = (r0 / tilesX) * 256;
        tileN = (r0 % tilesX) * 256;
        cTileM = tileM; cTileN = tileN;
        NT = K >> 6;
    }

    const int tid  = threadIdx.x;
    const int lane = tid & 63;
    const int wave = tid >> 6;
    const int wr   = wave >> 2;
    const int wc   = wave & 3;
    const int la   = lane & 15;
    const int kg   = lane >> 4;

    auto stageA = [&](int buf, int mq, int kt) {
        _Float16* dst = &lds[buf * 32768 + mq * 8192];
        const int k0 = kt * 64;
        #pragma unroll
        for (int i = 0; i < 2; ++i) {
            const int U = i * 512 + tid;
            const int R = U >> 3, s = U & 7;
            const int gr = tileM + (R >> 6) * 128 + mq * 64 + (R & 63);
            gload_lds16(&A[(long)gr * lda + k0 + ((s ^ (R & 7)) << 3)], dst + U * 8);
        }
    };
    auto stageB = [&](int buf, int nq, int kt) {
        _Float16* dst = &lds[buf * 32768 + 16384 + nq * 8192];
        const int k0 = kt * 64;
        #pragma unroll
        for (int i = 0; i < 2; ++i) {
            const int U = i * 512 + tid;
            const int R = U >> 3, s = U & 7;
            const int gn = tileN + (R >> 5) * 64 + nq * 32 + (R & 31);
            gload_lds16(&B[(long)gn * ldb + k0 + ((s ^ (R & 7)) << 3)], dst + U * 8);
        }
    };

    f4 acc[8][4] = {};
    h8 af[4][2];
    h8 bf[2][2][2];

    auto readA = [&](int buf, int mq) {
        const _Float16* Ab = &lds[buf * 32768 + mq * 8192];
        #pragma unroll
        for (int mi = 0; mi < 4; ++mi)
            #pragma unroll
            for (int kk = 0; kk < 2; ++kk) {
                const int R = wr * 64 + mi * 16 + la;
                const int s = kk * 4 + kg;
                af[mi][kk] = *(const h8*)&Ab[R * 64 + ((s ^ (R & 7)) << 3)];
            }
    };
    auto readB = [&](int buf, int nq) {
        const _Float16* Bb = &lds[buf * 32768 + 16384 + nq * 8192];
        #pragma unroll
        for (int ni = 0; ni < 2; ++ni)
            #pragma unroll
            for (int kk = 0; kk < 2; ++kk) {
                const int R = wc * 32 + ni * 16 + la;
                const int s = kk * 4 + kg;
                bf[nq][ni][kk] = *(const h8*)&Bb[R * 64 + ((s ^ (R & 7)) << 3)];
            }
    };
    auto mfmaQ = [&](int mq, int nq) {
        __builtin_amdgcn_s_setprio(1);
        #pragma unroll
        for (int mi = 0; mi < 4; ++mi)
            #pragma unroll
            for (int ni = 0; ni < 2; ++ni)
                #pragma unroll
                for (int kk = 0; kk < 2; ++kk)
                    acc[mq * 4 + mi][nq * 2 + ni] =
                        __builtin_amdgcn_mfma_f32_16x16x32_f16(
                            af[mi][kk], bf[nq][ni][kk],
                            acc[mq * 4 + mi][nq * 2 + ni], 0, 0, 0);
        __builtin_amdgcn_s_setprio(0);
    };

    // prologue: tile0 (4 stages=8 loads) + tile1 A0/B0; vmcnt(4)=tile0 landed.
    stageA(0, 0, 0); stageA(0, 1, 0); stageB(0, 0, 0); stageB(0, 1, 0);
    if (NT > 1) {
        stageA(1, 0, 1); stageB(1, 0, 1);
        asm volatile("s_waitcnt vmcnt(4)" ::: "memory");
    } else {
        asm volatile("s_waitcnt vmcnt(0)" ::: "memory");
    }
    __builtin_amdgcn_sched_barrier(0);
    __builtin_amdgcn_s_barrier();
    readB(0, 0);   // B0[0] -> bf[0]  (P4-style pre-read; landed per vmcnt above)

    for (int j = 0; j < NT; ++j) {
        const int buf = j & 1;
        // P1: 8 reads (A0[j]); MFMA Q00 uses af + bf[0] (read last P4/prologue)
        readA(buf, 0);
        if (j + 1 < NT) stageA(buf ^ 1, 1, j + 1);
        __builtin_amdgcn_s_barrier();
        asm volatile("s_waitcnt lgkmcnt(0)" ::: "memory");
        __builtin_amdgcn_sched_barrier(0);
        mfmaQ(0, 0);
        __builtin_amdgcn_s_barrier();
        // P2: 4 reads (B1[j])
        readB(buf, 1);
        if (j + 1 < NT) stageB(buf ^ 1, 1, j + 1);
        __builtin_amdgcn_s_barrier();
        asm volatile("s_waitcnt lgkmcnt(0)" ::: "memory");
        __builtin_amdgcn_sched_barrier(0);
        mfmaQ(0, 1);
        __builtin_amdgcn_s_barrier();
        // P3: 8 reads (A1[j]) + vmcnt(6) so P4 can read S(j-1,P4)
        readA(buf, 1);
        if (j + 2 < NT) stageA(buf, 0, j + 2);
        __builtin_amdgcn_s_barrier();
        asm volatile("s_waitcnt lgkmcnt(0)" ::: "memory");
        __builtin_amdgcn_sched_barrier(0);
        mfmaQ(1, 0);
        if (j + 2 < NT) {
            asm volatile("s_waitcnt vmcnt(6)" ::: "memory");
        } else if (j + 1 < NT) {
            asm volatile("s_waitcnt vmcnt(4)" ::: "memory");
        }
        __builtin_amdgcn_sched_barrier(0);
        __builtin_amdgcn_s_barrier();
        // P4: 4 reads (B0[j+1] -> bf[0], for next tile's Q00)
        if (j + 1 < NT) readB(buf ^ 1, 0);
        if (j + 2 < NT) stageB(buf, 0, j + 2);
        __builtin_amdgcn_s_barrier();
        mfmaQ(1, 1);
        if (j + 2 < NT) {
            asm volatile("s_waitcnt vmcnt(4)" ::: "memory");
        } else if (j + 1 < NT) {
            asm volatile("s_waitcnt vmcnt(0)" ::: "memory");
        }
        __builtin_amdgcn_sched_barrier(0);
        __builtin_amdgcn_s_barrier();
    }

    #pragma unroll
    for (int mf = 0; mf < 8; ++mf) {
        #pragma unroll
        for (int nf = 0; nf < 4; ++nf) {
            const int col = cTileN + wc * 64 + nf * 16 + la;
            #pragma unroll
            for (int jj = 0; jj < 4; ++jj) {
                const int row = cTileM + wr * 128 + mf * 16 + kg * 4 + jj;
                float v = acc[mf][nf][jj] * alpha;
                if (BIAS == 1) v += pc1[col];
                C[(long)row * ldc + col] = (OutT)v;
            }
        }
    }
}

// 64x64 NT GEMM (chain). z >= zSplit -> (A2,B2,C2), z'=0.
template<int BIAS>
__global__ __launch_bounds__(256) void gemm64(
    const _Float16* __restrict__ A, const _Float16* __restrict__ B,
    _Float16* __restrict__ C,
    const _Float16* __restrict__ A2, const _Float16* __restrict__ B2,
    _Float16* __restrict__ C2, int zSplit,
    int K, int lda, int ldb, int ldc, int tilesX, int perZ,
    long aZ, long bZ, long cZ,
    const float* __restrict__ bc1, long bc1Z,
    const float* __restrict__ br1, long br1Z,
    const float* __restrict__ bc2, long bc2Z,
    const float* __restrict__ br2, long br2Z,
    float alpha, float beta)
{
    __shared__ _Float16 As[64 * 64];
    __shared__ _Float16 Bs[64 * 64];

    const int L  = xcd_swz(blockIdx.x, gridDim.x);
    int z        = L / perZ;
    const int r0 = L - z * perZ;
    if (z >= zSplit) { A = A2; B = B2; C = C2; z = 0; }
    A += (long)z * aZ;
    B += (long)z * bZ;
    C += (long)z * cZ;
    const float* pc1 = nullptr; const float* pr1 = nullptr;
    const float* pc2 = nullptr; const float* pr2 = nullptr;
    if (BIAS == 3) {
        pc1 = bc1 + (long)z * bc1Z; pr1 = br1 + (long)z * br1Z;
        pc2 = bc2 + (long)z * bc2Z; pr2 = br2 + (long)z * br2Z;
    }

    const int tileM = (r0 / tilesX) * 64;
    const int tileN = (r0 % tilesX) * 64;
    const int tid   = threadIdx.x;
    const int lane  = tid & 63;
    const int wave  = tid >> 6;
    const int wm    = (wave >> 1) * 32;
    const int wn    = (wave & 1) * 32;
    const int srow  = tid >> 3;
    const int sslot = tid & 7;

    f4 acc[2][2] = {};
    const int arow = lane & 15;
    const int kg   = lane >> 4;

    for (int k0 = 0; k0 < K; k0 += 64) {
        #pragma unroll
        for (int i = 0; i < 2; ++i) {
            const int row   = i * 32 + srow;
            const int gslot = sslot ^ (row & 7);
            gload_lds16(&A[(long)(tileM + row) * lda + k0 + gslot * 8],
                        &As[row * 64 + sslot * 8]);
            gload_lds16(&B[(long)(tileN + row) * ldb + k0 + gslot * 8],
                        &Bs[row * 64 + sslot * 8]);
        }
        __syncthreads();

        #pragma unroll
        for (int kk = 0; kk < 64; kk += 32) {
            h8 af[2], bf[2];
            #pragma unroll
            for (int m = 0; m < 2; ++m) {
                const int rr   = wm + m * 16 + arow;
                const int slot = (kk >> 3) + kg;
                af[m] = *(const h8*)&As[rr * 64 + ((slot ^ (rr & 7)) << 3)];
            }
            #pragma unroll
            for (int n = 0; n < 2; ++n) {
                const int rr   = wn + n * 16 + arow;
                const int slot = (kk >> 3) + kg;
                bf[n] = *(const h8*)&Bs[rr * 64 + ((slot ^ (rr & 7)) << 3)];
            }
            #pragma unroll
            for (int m = 0; m < 2; ++m)
                #pragma unroll
                for (int n = 0; n < 2; ++n)
                    acc[m][n] = __builtin_amdgcn_mfma_f32_16x16x32_f16(
                        af[m], bf[n], acc[m][n], 0, 0, 0);
        }
        __syncthreads();
    }

    #pragma unroll
    for (int m = 0; m < 2; ++m) {
        #pragma unroll
        for (int n = 0; n < 2; ++n) {
            const int col = tileN + wn + n * 16 + arow;
            #pragma unroll
            for (int j = 0; j < 4; ++j) {
                const int row = tileM + wm + m * 16 + (lane >> 4) * 4 + j;
                float v = acc[m][n][j] * alpha;
                if (BIAS == 3) v += beta * (pc1[col] * pr1[row] + pc2[col] * pr2[row]);
                C[(long)row * ldc + col] = (_Float16)v;
            }
        }
    }
}

extern "C" void kernel_launch(void* const* d_in, const int* in_sizes, int n_in,
                              void* d_out, int out_size, void* d_ws, size_t ws_size,
                              hipStream_t stream)
{
    const float* x  = (const float*)d_in[0];
    const float* Wq = (const float*)d_in[1];
    const float* bq = (const float*)d_in[2];
    const float* Wk = (const float*)d_in[3];
    const float* bk = (const float*)d_in[4];
    const float* Wv = (const float*)d_in[5];
    const float* bv = (const float*)d_in[6];
    float* out = (float*)d_out;

    const long DD = (long)DM * DM;
    const long DS = (long)DM * SEQ;
    const long MB = 1024l * 1024;

    char* base = (char*)d_ws;
    _Float16* xh   = (_Float16*)base;
    _Float16* xt   = (_Float16*)(base + 32 * MB);
    _Float16* Gh   = xt;                                  // reuse after xt dead
    _Float16* Ph   = (_Float16*)(base + 40 * MB);
    _Float16* Rth  = (_Float16*)(base + 48 * MB);
    _Float16* Wqt  = (_Float16*)(base + 64 * MB);
    _Float16* Wvh  = (_Float16*)(base + 66 * MB);
    _Float16* Wkt  = (_Float16*)(base + 68 * MB);
    _Float16* Mh   = (_Float16*)(base + 70 * MB);
    float*    vecs = (float*)(base + 72 * MB);
    float*    u2   = vecs;                // 4096
    float*    qk   = vecs + 4096;         // 1024
    float*    kb   = vecs + 5120;         // 1024
    float*    xs   = vecs + 6144;         // 4096
    float*    qw   = vecs + 10240;        // 4096
    float*    cv   = vecs + 14336;        // 4096
    float*    sv   = vecs + 18432;        // 8
    _Float16* parts = (_Float16*)d_out;   // 240 x 256^2 fp16 = 30MB scratch

    // 0) zero xs (atomically accumulated by cvt_all)
    hipMemsetAsync(xs, 0, BATCH * DM * sizeof(float), stream);

    // 1) all converts + fused col-sums
    cvt_all<<<4864, 256, 0, stream>>>(x, Wq, Wk, Wv, xt, xh, Wqt, Wkt, Wvh, xs);

    // 2) u2 (batched x4), qk, kb
    gemv_misc<<<768, 256, 0, stream>>>(Wvh, Wqt, Wkt, xs, bv, bk, bq, u2, qk, kb);

    // 3) Triangular Gram: parts[job*6+s] = lower-tri 256^2 tile, K-slice s
    gemm8p<_Float16, 0, 1><<<240, 512, 0, stream>>>(
        xt, xt, parts, 4096, SEQ, SEQ, 256, 0, 0,
        DS, DS, 65536, 1, 0, 0, nullptr, 0, 1.0f);

    // 4) Gh = (1/32)*sum_s parts, mirrored (+ block 640: sv)
    reduce_tri<<<641, 256, 0, stream>>>(parts, Gh, kb, xs, bq, bk, sv);

    // 5) Ph[b] = Wv.Gh[b] (z<4)  ||  Mh = Wqt.Wkt^T (z=4)
    gemm64<0><<<1280, 256, 0, stream>>>(
        Wvh, Gh, Ph, Wqt, Wkt, Mh, 4,
        1024, DM, DM, DM, 16, 256,
        0, DD, DD,
        nullptr, 0, nullptr, 0, nullptr, 0, nullptr, 0, 1.0f, 0.f);

    // 6) cv (from Ph,kb,sv) + qw (= Mh.xs, batched x4)
    gemv_cvqw<<<1280, 256, 0, stream>>>(Ph, Mh, kb, xs, u2, bv, sv, cv, qw);

    // 7) Rt[b] = Ph.M^T + (1/32)(qk ox u2 + qw ox bv)
    gemm64<3><<<1024, 256, 0, stream>>>(
        Ph, Mh, Rth, nullptr, nullptr, nullptr, 99,
        1024, DM, DM, DM, 16, 256,
        DD, 0, DD,
        qk, 0, u2, 1024, qw, 1024, bv, 0, 1.0f, 0.03125f);

    // 8) E[b] = xh.Rt^T + cv -> fp32 out
    gemm8p<float, 1, 0><<<256, 512, 0, stream>>>(
        xh, Rth, out, 1024, DM, DM, DM, 4, 64,
        DS, DD, DS, 1, 0, 0, cv, 1024, 1.0f);
}

// Round 15
// 151.325 us; speedup vs baseline: 1.0043x; 1.0043x over previous
//
#include <hip/hip_runtime.h>
#include <hip/hip_fp16.h>

// EfficientAttention  B=4, S=4096, D=1024, fp32 in/out.
//   G[b] = x^T x (lower-tri 256^2 tiles, split-K=6, fp16 parts in d_out)
//   Gh = (1/32) sum parts (mirrored); Ph[b] = Wv Gh[b] (has the 1/32)
//   M = Wq^T Wk;  w[b] = Wk xs[b];  qw[b] = Wq^T w[b];  kb = Wk^T bq;  qk = Wq^T bk
//   sv0 = bq.bk;  sv_b = kb.xs[b]
//   Rt[b] = Ph M^T + (1/32)(u2 ox qk + bv ox qw[b])
//   cv[b] = Ph kb + (1/32)(sv0 u2 + sv_b bv)   [computed in the Rt launch]
//   E[b]  = x Rt^T + cv
// gemm8p: R13-frozen 8-phase 256x256 schedule (12/4/8/0 reads, vmcnt(4)@P4).

#define BATCH 4
#define SEQ   4096
#define DM    1024

typedef _Float16 h8 __attribute__((ext_vector_type(8)));
typedef _Float16 h4 __attribute__((ext_vector_type(4)));
typedef float    f4 __attribute__((ext_vector_type(4)));

__device__ inline void gload_lds16(const _Float16* g, _Float16* l) {
    __builtin_amdgcn_global_load_lds(
        (const __attribute__((address_space(1))) void*)g,
        (__attribute__((address_space(3))) void*)l,
        16, 0, 0);
}

__device__ inline int xcd_swz(int bid, int grid) {
    const int q = grid >> 3;
    return (bid & 7) * q + (bid >> 3);
}

__device__ inline float doth(const _Float16* wr, const float* v, int lane) {
    float s = 0.f;
    #pragma unroll
    for (int i = 0; i < 2; ++i) {
        const int k = i * 512 + lane * 8;
        h8 wv = *(const h8*)&wr[k];
        f4 v0 = *(const f4*)&v[k];
        f4 v1 = *(const f4*)&v[k + 4];
        s += (float)wv[0] * v0.x + (float)wv[1] * v0.y +
             (float)wv[2] * v0.z + (float)wv[3] * v0.w +
             (float)wv[4] * v1.x + (float)wv[5] * v1.y +
             (float)wv[6] * v1.z + (float)wv[7] * v1.w;
    }
    return s;
}
// fp16 weight row dotted against 4 f32 vectors (stride DM) at once
__device__ inline void doth4(const _Float16* wr, const float* xs, int lane, float* s) {
    #pragma unroll
    for (int i = 0; i < 2; ++i) {
        const int k = i * 512 + lane * 8;
        h8 wv = *(const h8*)&wr[k];
        #pragma unroll
        for (int b = 0; b < 4; ++b) {
            const float* v = xs + b * DM + k;
            f4 v0 = *(const f4*)&v[0];
            f4 v1 = *(const f4*)&v[4];
            s[b] += (float)wv[0] * v0.x + (float)wv[1] * v0.y +
                    (float)wv[2] * v0.z + (float)wv[3] * v0.w +
                    (float)wv[4] * v1.x + (float)wv[5] * v1.y +
                    (float)wv[6] * v1.z + (float)wv[7] * v1.w;
        }
    }
}
__device__ inline float dotf(const float* a, const float* b, int lane) {
    float s = 0.f;
    #pragma unroll
    for (int i = 0; i < 4; ++i) {
        const int k = i * 256 + lane * 4;
        f4 x = *(const f4*)&a[k];
        f4 y = *(const f4*)&b[k];
        s += x.x * y.x + x.y * y.y + x.z * y.z + x.w * y.w;
    }
    return s;
}
__device__ inline float wred(float s) {
    #pragma unroll
    for (int off = 32; off; off >>= 1) s += __shfl_down(s, off);
    return s;
}

// One launch: x batches (bid<4096: transpose+RM+colsum) and weights
// (bid>=4096: z=0 Wq->Wqt(T), z=1 Wk->Wkt(T)+Wkh(RM), z=2 Wv->Wvh(RM)).
__global__ __launch_bounds__(256) void cvt_all(
    const float* __restrict__ x, const float* __restrict__ Wq,
    const float* __restrict__ Wk, const float* __restrict__ Wv,
    _Float16* __restrict__ xt, _Float16* __restrict__ xh,
    _Float16* __restrict__ Wqt, _Float16* __restrict__ Wkt,
    _Float16* __restrict__ Wkh, _Float16* __restrict__ Wvh,
    float* __restrict__ xs)
{
    __shared__ float tile[64][65];
    __shared__ float red[4][64];
    const int bid = blockIdx.x;
    const int t   = threadIdx.x;
    const int tr  = t >> 4;
    const int tc  = (t & 15) * 4;

    const float* src;
    _Float16 *dstT = nullptr, *dstRM = nullptr;
    int r0, c0, C, R;
    bool isX = bid < 4096;
    if (isX) {
        const int b  = bid >> 10;
        const int tt = bid & 1023;
        r0 = (tt >> 4) * 64; c0 = (tt & 15) * 64;
        R = SEQ; C = DM;
        src   = x  + (long)b * SEQ * DM;
        dstT  = xt + (long)b * SEQ * DM;
        dstRM = xh + (long)b * SEQ * DM;
        xs   += b * DM;
    } else {
        const int wb = bid - 4096;
        const int z  = wb >> 8;
        const int tt = wb & 255;
        r0 = (tt >> 4) * 64; c0 = (tt & 15) * 64;
        R = DM; C = DM;
        src = z == 0 ? Wq : (z == 1 ? Wk : Wv);
        if (z == 0) { dstT = Wqt; }
        else if (z == 1) { dstT = Wkt; dstRM = Wkh; }
        else dstRM = Wvh;
    }

    #pragma unroll
    for (int i = 0; i < 4; ++i) {
        const int r = tr + i * 16;
        f4 v = *(const f4*)&src[(long)(r0 + r) * C + c0 + tc];
        tile[r][tc + 0] = v.x; tile[r][tc + 1] = v.y;
        tile[r][tc + 2] = v.z; tile[r][tc + 3] = v.w;
        if (dstRM) {
            h4 h = { (_Float16)v.x, (_Float16)v.y, (_Float16)v.z, (_Float16)v.w };
            *(h4*)&dstRM[(long)(r0 + r) * C + c0 + tc] = h;
        }
    }
    __syncthreads();
    if (dstT) {
        #pragma unroll
        for (int i = 0; i < 4; ++i) {
            const int c = tr + i * 16;
            h4 h = { (_Float16)tile[tc + 0][c], (_Float16)tile[tc + 1][c],
                     (_Float16)tile[tc + 2][c], (_Float16)tile[tc + 3][c] };
            *(h4*)&dstT[(long)(c0 + c) * R + r0 + tc] = h;
        }
    }
    if (isX) {
        const int cc = t & 63;
        const int rb = (t >> 6) * 16;
        float ps = 0.f;
        #pragma unroll
        for (int r = 0; r < 16; ++r) ps += tile[rb + r][cc];
        red[t >> 6][cc] = ps;
        __syncthreads();
        if (t < 64)
            atomicAdd(&xs[c0 + t], red[0][t] + red[1][t] + red[2][t] + red[3][t]);
    }
}

// gw<1024:  e: u2[b,e] = Wvh[e].xs[b] + S*bv[e]   (4 batches/wave)
// gw<2048:  i: qk[i] = Wqt[i].bk
// gw<3072:  j: kb[j] = Wkt[j].bq
// gw<4096:  d: w[b,d] = Wkh[d].xs[b]              (4 batches/wave)
__global__ __launch_bounds__(256) void gemv_misc(
    const _Float16* __restrict__ Wvh, const _Float16* __restrict__ Wqt,
    const _Float16* __restrict__ Wkt, const _Float16* __restrict__ Wkh,
    const float* __restrict__ xs, const float* __restrict__ bv,
    const float* __restrict__ bk, const float* __restrict__ bq,
    float* __restrict__ u2, float* __restrict__ qk,
    float* __restrict__ kb, float* __restrict__ w)
{
    const int gw   = blockIdx.x * 4 + (threadIdx.x >> 6);
    const int lane = threadIdx.x & 63;
    if (gw < 1024) {
        float s[4] = {};
        doth4(Wvh + (long)gw * DM, xs, lane, s);
        #pragma unroll
        for (int b = 0; b < 4; ++b) {
            float r = wred(s[b]);
            if (lane == 0) u2[b * DM + gw] = r + (float)SEQ * bv[gw];
        }
    } else if (gw < 2048) {
        float s = wred(doth(Wqt + (long)(gw - 1024) * DM, bk, lane));
        if (lane == 0) qk[gw - 1024] = s;
    } else if (gw < 3072) {
        float s = wred(doth(Wkt + (long)(gw - 2048) * DM, bq, lane));
        if (lane == 0) kb[gw - 2048] = s;
    } else {
        const int d = gw - 3072;
        float s[4] = {};
        doth4(Wkh + (long)d * DM, xs, lane, s);
        #pragma unroll
        for (int b = 0; b < 4; ++b) {
            float r = wred(s[b]);
            if (lane == 0) w[b * DM + d] = r;
        }
    }
}

// Triangular reduce+mirror (blocks 0..639); qw gemv (640..895); sv (896).
__global__ __launch_bounds__(256) void reduce_tri(
    const _Float16* __restrict__ parts, _Float16* __restrict__ Gh,
    const _Float16* __restrict__ Wqt, const float* __restrict__ w,
    const float* __restrict__ kb, const float* __restrict__ xs,
    const float* __restrict__ bq, const float* __restrict__ bk,
    float* __restrict__ qw, float* __restrict__ sv)
{
    const int bid = blockIdx.x;
    if (bid >= 640) {
        const int wv   = threadIdx.x >> 6;
        const int lane = threadIdx.x & 63;
        if (bid < 896) {
            const int i = (bid - 640) * 4 + wv;   // 0..1023
            float s[4] = {};
            doth4(Wqt + (long)i * DM, w, lane, s);
            #pragma unroll
            for (int b = 0; b < 4; ++b) {
                float r = wred(s[b]);
                if (lane == 0) qw[b * DM + i] = r;
            }
        } else {
            float s = wred(dotf(kb, xs + wv * DM, lane));
            if (lane == 0) sv[1 + wv] = s;
            if (wv == 0) {
                float s0 = wred(dotf(bq, bk, lane));
                if (lane == 0) sv[0] = s0;
            }
        }
        return;
    }
    __shared__ _Float16 lds[64][72];
    const int job = bid >> 4;
    const int ch  = bid & 15;
    const int b   = job / 10;
    const int p   = job - b * 10;
    const int ti  = p >= 6 ? 3 : (p >= 3 ? 2 : (p >= 1 ? 1 : 0));
    const int tj  = p - ((ti * (ti + 1)) >> 1);
    const int li  = (ch >> 2) * 64;
    const int lj  = (ch & 3) * 64;
    const int t   = threadIdx.x;
    const int c8  = (t & 7) * 8;
    const long DD_ = (long)DM * DM;

    h8 o[2];
    #pragma unroll
    for (int h = 0; h < 2; ++h) {
        const int r = (t >> 3) + h * 32;
        float a[8] = {};
        #pragma unroll
        for (int s = 0; s < 6; ++s) {
            const _Float16* src = parts + ((long)(job * 6 + s) << 16);
            h8 v = *(const h8*)&src[(li + r) * 256 + lj + c8];
            #pragma unroll
            for (int j = 0; j < 8; ++j) a[j] += (float)v[j];
        }
        #pragma unroll
        for (int j = 0; j < 8; ++j) o[h][j] = (_Float16)(a[j] * 0.03125f);
        *(h8*)&Gh[b * DD_ + (long)(ti * 256 + li + r) * DM + tj * 256 + lj + c8] = o[h];
        *(h8*)&lds[r][c8] = o[h];
    }
    if (ti != tj) {
        __syncthreads();
        #pragma unroll
        for (int h = 0; h < 2; ++h) {
            const int r = (t >> 3) + h * 32;
            h8 m;
            #pragma unroll
            for (int j = 0; j < 8; ++j) m[j] = lds[c8 + j][r];
            *(h8*)&Gh[b * DD_ + (long)(tj * 256 + lj + r) * DM + ti * 256 + li + c8] = m;
        }
    }
}

// ---------------------------------------------------------------------------
// 8-phase 256x256 NT GEMM — R13-FROZEN schedule. TRI=1: triangular Gram mode.
// ---------------------------------------------------------------------------
template<typename OutT, int BIAS, int TRI>
__global__ __launch_bounds__(512, 1) void gemm8p(
    const _Float16* __restrict__ A, const _Float16* __restrict__ B,
    OutT* __restrict__ C,
    int K, int lda, int ldb, int ldc, int tilesX, int perZ,
    long aZ, long bZ, long cZ, int sk, long aK, long bK,
    const float* __restrict__ bc1, long bc1Z, float alpha)
{
    __shared__ _Float16 lds[2 * 32768];   // 128 KiB

    const int L = xcd_swz(blockIdx.x, gridDim.x);
    int tileM, tileN, cTileM, cTileN, NT;
    const float* pc1 = nullptr;
    if (TRI) {
        const int job = L / 6;
        const int s   = L - job * 6;
        const int b   = job / 10;
        const int p   = job - b * 10;
        const int ti  = p >= 6 ? 3 : (p >= 3 ? 2 : (p >= 1 ? 1 : 0));
        const int tj  = p - ((ti * (ti + 1)) >> 1);
        const int kOff = s < 4 ? s * 704 : 2816 + (s - 4) * 640;
        NT = s < 4 ? 11 : 10;
        A += (long)b * aZ + kOff;
        B += (long)b * aZ + kOff;
        C += (long)(job * 6 + s) * cZ;
        tileM = ti * 256; tileN = tj * 256;
        cTileM = 0; cTileN = 0;
    } else {
        const int z  = L / perZ;
        const int r0 = L - z * perZ;
        const int zb = z / sk;
        const int zk = z - zb * sk;
        A += (long)zb * aZ + (long)zk * aK;
        B += (long)zb * bZ + (long)zk * bK;
        C += (long)z * cZ;
        if (BIAS == 1) pc1 = bc1 + (long)zb * bc1Z;
        tileM = (r0 / tilesX) * 256;
        tileN = (r0 % tilesX) * 256;
        cTileM = tileM; cTileN = tileN;
        NT = K >> 6;
    }

    const int tid  = threadIdx.x;
    const int lane = tid & 63;
    const int wave = tid >> 6;
    const int wr   = wave >> 2;
    const int wc   = wave & 3;
    const int la   = lane & 15;
    const int kg   = lane >> 4;

    auto stageA = [&](int buf, int mq, int kt) {
        _Float16* dst = &lds[buf * 32768 + mq * 8192];
        const int k0 = kt * 64;
        #pragma unroll
        for (int i = 0; i < 2; ++i) {
            const int U = i * 512 + tid;
            const int R = U >> 3, s = U & 7;
            const int gr = tileM + (R >> 6) * 128 + mq * 64 + (R & 63);
            gload_lds16(&A[(long)gr * lda + k0 + ((s ^ (R & 7)) << 3)], dst + U * 8);
        }
    };
    auto stageB = [&](int buf, int nq, int kt) {
        _Float16* dst = &lds[buf * 32768 + 16384 + nq * 8192];
        const int k0 = kt * 64;
        #pragma unroll
        for (int i = 0; i < 2; ++i) {
            const int U = i * 512 + tid;
            const int R = U >> 3, s = U & 7;
            const int gn = tileN + (R >> 5) * 64 + nq * 32 + (R & 31);
            gload_lds16(&B[(long)gn * ldb + k0 + ((s ^ (R & 7)) << 3)], dst + U * 8);
        }
    };

    f4 acc[8][4] = {};
    h8 af[4][2];
    h8 bf[2][2][2];

    auto readA = [&](int buf, int mq) {
        const _Float16* Ab = &lds[buf * 32768 + mq * 8192];
        #pragma unroll
        for (int mi = 0; mi < 4; ++mi)
            #pragma unroll
            for (int kk = 0; kk < 2; ++kk) {
                const int R = wr * 64 + mi * 16 + la;
                const int s = kk * 4 + kg;
                af[mi][kk] = *(const h8*)&Ab[R * 64 + ((s ^ (R & 7)) << 3)];
            }
    };
    auto readB = [&](int buf, int nq) {
        const _Float16* Bb = &lds[buf * 32768 + 16384 + nq * 8192];
        #pragma unroll
        for (int ni = 0; ni < 2; ++ni)
            #pragma unroll
            for (int kk = 0; kk < 2; ++kk) {
                const int R = wc * 32 + ni * 16 + la;
                const int s = kk * 4 + kg;
                bf[nq][ni][kk] = *(const h8*)&Bb[R * 64 + ((s ^ (R & 7)) << 3)];
            }
    };
    auto mfmaQ = [&](int mq, int nq) {
        __builtin_amdgcn_s_setprio(1);
        #pragma unroll
        for (int mi = 0; mi < 4; ++mi)
            #pragma unroll
            for (int ni = 0; ni < 2; ++ni)
                #pragma unroll
                for (int kk = 0; kk < 2; ++kk)
                    acc[mq * 4 + mi][nq * 2 + ni] =
                        __builtin_amdgcn_mfma_f32_16x16x32_f16(
                            af[mi][kk], bf[nq][ni][kk],
                            acc[mq * 4 + mi][nq * 2 + ni], 0, 0, 0);
        __builtin_amdgcn_s_setprio(0);
    };

    stageA(0, 0, 0); stageA(0, 1, 0); stageB(0, 0, 0); stageB(0, 1, 0);
    if (NT > 1) {
        stageA(1, 0, 1); stageB(1, 0, 1);
        asm volatile("s_waitcnt vmcnt(4)" ::: "memory");
    } else {
        asm volatile("s_waitcnt vmcnt(0)" ::: "memory");
    }
    __builtin_amdgcn_sched_barrier(0);
    __builtin_amdgcn_s_barrier();

    for (int j = 0; j < NT; ++j) {
        const int buf = j & 1;
        // P1
        readA(buf, 0); readB(buf, 0);
        if (j + 1 < NT) stageA(buf ^ 1, 1, j + 1);
        asm volatile("s_waitcnt lgkmcnt(8)" ::: "memory");
        __builtin_amdgcn_s_barrier();
        asm volatile("s_waitcnt lgkmcnt(0)" ::: "memory");
        __builtin_amdgcn_sched_barrier(0);
        mfmaQ(0, 0);
        __builtin_amdgcn_s_barrier();
        // P2
        readB(buf, 1);
        if (j + 1 < NT) stageB(buf ^ 1, 1, j + 1);
        __builtin_amdgcn_s_barrier();
        asm volatile("s_waitcnt lgkmcnt(0)" ::: "memory");
        __builtin_amdgcn_sched_barrier(0);
        mfmaQ(0, 1);
        __builtin_amdgcn_s_barrier();
        // P3
        readA(buf, 1);
        if (j + 2 < NT) stageA(buf, 0, j + 2);
        __builtin_amdgcn_s_barrier();
        asm volatile("s_waitcnt lgkmcnt(0)" ::: "memory");
        __builtin_amdgcn_sched_barrier(0);
        mfmaQ(1, 0);
        __builtin_amdgcn_s_barrier();
        // P4
        if (j + 2 < NT) stageB(buf, 0, j + 2);
        __builtin_amdgcn_s_barrier();
        mfmaQ(1, 1);
        if (j + 2 < NT) {
            asm volatile("s_waitcnt vmcnt(4)" ::: "memory");
        } else if (j + 1 < NT) {
            asm volatile("s_waitcnt vmcnt(0)" ::: "memory");
        }
        __builtin_amdgcn_sched_barrier(0);
        __builtin_amdgcn_s_barrier();
    }

    #pragma unroll
    for (int mf = 0; mf < 8; ++mf) {
        #pragma unroll
        for (int nf = 0; nf < 4; ++nf) {
            const int col = cTileN + wc * 64 + nf * 16 + la;
            #pragma unroll
            for (int jj = 0; jj < 4; ++jj) {
                const int row = cTileM + wr * 128 + mf * 16 + kg * 4 + jj;
                float v = acc[mf][nf][jj] * alpha;
                if (BIAS == 1) v += pc1[col];
                C[(long)row * ldc + col] = (OutT)v;
            }
        }
    }
}

// 64x64 NT GEMM (chain).
// BIAS==0: z >= zSplit -> (A2,B2,C2), z'=0  (Ph || Mh co-launch).
// BIAS==3: rank-1 epilogue; blocks with z >= zSplit run the cv gemv instead:
//   cv[b,e] = Ph[b,e,:].kb + (sv0*u2 + sv_b*bv)/32
//   (kb/sv/cv passed via reinterpret-cast A2/B2/C2 slots; A=Ph.)
template<int BIAS>
__global__ __launch_bounds__(256) void gemm64(
    const _Float16* __restrict__ A, const _Float16* __restrict__ B,
    _Float16* __restrict__ C,
    const _Float16* __restrict__ A2, const _Float16* __restrict__ B2,
    _Float16* __restrict__ C2, int zSplit,
    int K, int lda, int ldb, int ldc, int tilesX, int perZ,
    long aZ, long bZ, long cZ,
    const float* __restrict__ bc1, long bc1Z,
    const float* __restrict__ br1, long br1Z,
    const float* __restrict__ bc2, long bc2Z,
    const float* __restrict__ br2, long br2Z,
    float alpha, float beta)
{
    __shared__ _Float16 As[64 * 64];
    __shared__ _Float16 Bs[64 * 64];

    const int L  = xcd_swz(blockIdx.x, gridDim.x);
    int z        = L / perZ;
    const int r0 = L - z * perZ;
    if (z >= zSplit) {
        if (BIAS == 3) {
            // cv gemv block: 4 waves, each one e with 4 batches.
            const float* kb = (const float*)A2;
            const float* sv = (const float*)B2;
            float*       cv = (float*)C2;
            const int wv   = threadIdx.x >> 6;
            const int lane = threadIdx.x & 63;
            const int e    = (L - zSplit * perZ) * 4 + wv;
            float s[4] = {};
            #pragma unroll
            for (int i = 0; i < 2; ++i) {
                const int k = i * 512 + lane * 8;
                f4 k0 = *(const f4*)&kb[k];
                f4 k1 = *(const f4*)&kb[k + 4];
                #pragma unroll
                for (int b = 0; b < 4; ++b) {
                    h8 pv = *(const h8*)&A[(long)b * aZ + (long)e * lda + k];
                    s[b] += (float)pv[0] * k0.x + (float)pv[1] * k0.y +
                            (float)pv[2] * k0.z + (float)pv[3] * k0.w +
                            (float)pv[4] * k1.x + (float)pv[5] * k1.y +
                            (float)pv[6] * k1.z + (float)pv[7] * k1.w;
                }
            }
            #pragma unroll
            for (int b = 0; b < 4; ++b) {
                float r = wred(s[b]);
                if (lane == 0)
                    cv[b * DM + e] = r + (sv[0] * br1[b * br1Z + e] +
                                          sv[1 + b] * br2[e]) * 0.03125f;
            }
            return;
        }
        A = A2; B = B2; C = C2; z = 0;
    }
    A += (long)z * aZ;
    B += (long)z * bZ;
    C += (long)z * cZ;
    const float* pc1 = nullptr; const float* pr1 = nullptr;
    const float* pc2 = nullptr; const float* pr2 = nullptr;
    if (BIAS == 3) {
        pc1 = bc1 + (long)z * bc1Z; pr1 = br1 + (long)z * br1Z;
        pc2 = bc2 + (long)z * bc2Z; pr2 = br2 + (long)z * br2Z;
    }

    const int tileM = (r0 / tilesX) * 64;
    const int tileN = (r0 % tilesX) * 64;
    const int tid   = threadIdx.x;
    const int lane  = tid & 63;
    const int wave  = tid >> 6;
    const int wm    = (wave >> 1) * 32;
    const int wn    = (wave & 1) * 32;
    const int srow  = tid >> 3;
    const int sslot = tid & 7;

    f4 acc[2][2] = {};
    const int arow = lane & 15;
    const int kg   = lane >> 4;

    for (int k0 = 0; k0 < K; k0 += 64) {
        #pragma unroll
        for (int i = 0; i < 2; ++i) {
            const int row   = i * 32 + srow;
            const int gslot = sslot ^ (row & 7);
            gload_lds16(&A[(long)(tileM + row) * lda + k0 + gslot * 8],
                        &As[row * 64 + sslot * 8]);
            gload_lds16(&B[(long)(tileN + row) * ldb + k0 + gslot * 8],
                        &Bs[row * 64 + sslot * 8]);
        }
        __syncthreads();

        #pragma unroll
        for (int kk = 0; kk < 64; kk += 32) {
            h8 af[2], bf[2];
            #pragma unroll
            for (int m = 0; m < 2; ++m) {
                const int rr   = wm + m * 16 + arow;
                const int slot = (kk >> 3) + kg;
                af[m] = *(const h8*)&As[rr * 64 + ((slot ^ (rr & 7)) << 3)];
            }
            #pragma unroll
            for (int n = 0; n < 2; ++n) {
                const int rr   = wn + n * 16 + arow;
                const int slot = (kk >> 3) + kg;
                bf[n] = *(const h8*)&Bs[rr * 64 + ((slot ^ (rr & 7)) << 3)];
            }
            #pragma unroll
            for (int m = 0; m < 2; ++m)
                #pragma unroll
                for (int n = 0; n < 2; ++n)
                    acc[m][n] = __builtin_amdgcn_mfma_f32_16x16x32_f16(
                        af[m], bf[n], acc[m][n], 0, 0, 0);
        }
        __syncthreads();
    }

    #pragma unroll
    for (int m = 0; m < 2; ++m) {
        #pragma unroll
        for (int n = 0; n < 2; ++n) {
            const int col = tileN + wn + n * 16 + arow;
            #pragma unroll
            for (int j = 0; j < 4; ++j) {
                const int row = tileM + wm + m * 16 + (lane >> 4) * 4 + j;
                float v = acc[m][n][j] * alpha;
                if (BIAS == 3) v += beta * (pc1[col] * pr1[row] + pc2[col] * pr2[row]);
                C[(long)row * ldc + col] = (_Float16)v;
            }
        }
    }
}

extern "C" void kernel_launch(void* const* d_in, const int* in_sizes, int n_in,
                              void* d_out, int out_size, void* d_ws, size_t ws_size,
                              hipStream_t stream)
{
    const float* x  = (const float*)d_in[0];
    const float* Wq = (const float*)d_in[1];
    const float* bq = (const float*)d_in[2];
    const float* Wk = (const float*)d_in[3];
    const float* bk = (const float*)d_in[4];
    const float* Wv = (const float*)d_in[5];
    const float* bv = (const float*)d_in[6];
    float* out = (float*)d_out;

    const long DD = (long)DM * DM;
    const long DS = (long)DM * SEQ;
    const long MB = 1024l * 1024;

    char* base = (char*)d_ws;
    _Float16* xh   = (_Float16*)base;
    _Float16* xt   = (_Float16*)(base + 32 * MB);
    _Float16* Gh   = xt;                                  // reuse after xt dead
    _Float16* Ph   = (_Float16*)(base + 40 * MB);
    _Float16* Rth  = (_Float16*)(base + 48 * MB);
    _Float16* Wqt  = (_Float16*)(base + 64 * MB);
    _Float16* Wvh  = (_Float16*)(base + 66 * MB);
    _Float16* Wkt  = (_Float16*)(base + 68 * MB);
    _Float16* Wkh  = (_Float16*)(base + 70 * MB);
    _Float16* Mh   = (_Float16*)(base + 72 * MB);
    float*    vecs = (float*)(base + 74 * MB);
    float*    u2   = vecs;                // 4096
    float*    qk   = vecs + 4096;         // 1024
    float*    kb   = vecs + 5120;         // 1024
    float*    xs   = vecs + 6144;         // 4096
    float*    qw   = vecs + 10240;        // 4096
    float*    cv   = vecs + 14336;        // 4096
    float*    sv   = vecs + 18432;        // 8
    float*    w    = vecs + 20480;        // 4096
    _Float16* parts = (_Float16*)d_out;   // 240 x 256^2 fp16 = 30MB scratch

    // 0) zero xs (atomically accumulated by cvt_all)
    hipMemsetAsync(xs, 0, BATCH * DM * sizeof(float), stream);

    // 1) all converts + fused col-sums
    cvt_all<<<4864, 256, 0, stream>>>(x, Wq, Wk, Wv, xt, xh, Wqt, Wkt, Wkh, Wvh, xs);

    // 2) u2, qk, kb, w  (batched gemvs)
    gemv_misc<<<1024, 256, 0, stream>>>(Wvh, Wqt, Wkt, Wkh, xs, bv, bk, bq,
                                        u2, qk, kb, w);

    // 3) Triangular Gram: parts[job*6+s] = lower-tri 256^2 tile, K-slice s
    gemm8p<_Float16, 0, 1><<<240, 512, 0, stream>>>(
        xt, xt, parts, 4096, SEQ, SEQ, 256, 0, 0,
        DS, DS, 65536, 1, 0, 0, nullptr, 0, 1.0f);

    // 4) Gh reduce+mirror (640) + qw gemv (256) + sv (1)
    reduce_tri<<<897, 256, 0, stream>>>(parts, Gh, Wqt, w, kb, xs, bq, bk, qw, sv);

    // 5) Ph[b] = Wv.Gh[b] (z<4)  ||  Mh = Wqt.Wkt^T (z=4)
    gemm64<0><<<1280, 256, 0, stream>>>(
        Wvh, Gh, Ph, Wqt, Wkt, Mh, 4,
        1024, DM, DM, DM, 16, 256,
        0, DD, DD,
        nullptr, 0, nullptr, 0, nullptr, 0, nullptr, 0, 1.0f, 0.f);

    // 6) Rt[b] = Ph.M^T + (1/32)(qk ox u2 + qw ox bv)   [blocks 1024..1279: cv]
    gemm64<3><<<1280, 256, 0, stream>>>(
        Ph, Mh, Rth,
        (const _Float16*)kb, (const _Float16*)sv, (_Float16*)cv, 4,
        1024, DM, DM, DM, 16, 256,
        DD, 0, DD,
        qk, 0, u2, 1024, qw, 1024, bv, 0, 1.0f, 0.03125f);

    // 7) E[b] = xh.Rt^T + cv -> fp32 out
    gemm8p<float, 1, 0><<<256, 512, 0, stream>>>(
        xh, Rth, out, 1024, DM, DM, DM, 4, 64,
        DS, DD, DS, 1, 0, 0, cv, 1024, 1.0f);
}

// Round 16
// 149.349 us; speedup vs baseline: 1.0176x; 1.0132x over previous
//
#include <hip/hip_runtime.h>
#include <hip/hip_fp16.h>

// EfficientAttention  B=4, S=4096, D=1024, fp32 in/out.  [R13 best-measured: 150.0 us]
//   G[b] = x^T x (lower-tri 256^2 tiles, split-K=6, fp16 parts in d_out)
//   Gh = (1/32) sum parts (mirrored); Ph[b] = Wv Gh[b] (has the 1/32)
//   M = Wq^T Wk;  qw[b] = M xs[b];  kb = Wk^T bq;  qk = Wq^T bk
//   sv0 = bq.bk;  sv_b = kb.xs[b]   (computed in reduce_tri's extra block)
//   Rt[b] = Ph M^T + (1/32)(u2 ox qk + bv ox qw[b])
//   cv[b] = Ph kb + (1/32)(sv0 u2 + sv_b bv);  E[b] = x Rt^T + cv
// Big GEMMs: 8-phase 256x256 (R7/R13-frozen schedule, T1..T5).

#define BATCH 4
#define SEQ   4096
#define DM    1024

typedef _Float16 h8 __attribute__((ext_vector_type(8)));
typedef _Float16 h4 __attribute__((ext_vector_type(4)));
typedef float    f4 __attribute__((ext_vector_type(4)));

__device__ inline void gload_lds16(const _Float16* g, _Float16* l) {
    __builtin_amdgcn_global_load_lds(
        (const __attribute__((address_space(1))) void*)g,
        (__attribute__((address_space(3))) void*)l,
        16, 0, 0);
}

__device__ inline int xcd_swz(int bid, int grid) {
    const int q = grid >> 3;
    return (bid & 7) * q + (bid >> 3);
}

__device__ inline float doth(const _Float16* wr, const float* v, int lane) {
    float s = 0.f;
    #pragma unroll
    for (int i = 0; i < 2; ++i) {
        const int k = i * 512 + lane * 8;
        h8 wv = *(const h8*)&wr[k];
        f4 v0 = *(const f4*)&v[k];
        f4 v1 = *(const f4*)&v[k + 4];
        s += (float)wv[0] * v0.x + (float)wv[1] * v0.y +
             (float)wv[2] * v0.z + (float)wv[3] * v0.w +
             (float)wv[4] * v1.x + (float)wv[5] * v1.y +
             (float)wv[6] * v1.z + (float)wv[7] * v1.w;
    }
    return s;
}
__device__ inline float dotf(const float* a, const float* b, int lane) {
    float s = 0.f;
    #pragma unroll
    for (int i = 0; i < 4; ++i) {
        const int k = i * 256 + lane * 4;
        f4 x = *(const f4*)&a[k];
        f4 y = *(const f4*)&b[k];
        s += x.x * y.x + x.y * y.y + x.z * y.z + x.w * y.w;
    }
    return s;
}
__device__ inline float wred(float s) {
    #pragma unroll
    for (int off = 32; off; off >>= 1) s += __shfl_down(s, off);
    return s;
}

// One launch: x batches (bid<4096: transpose+RM+colsum) and weights
// (bid>=4096: z=0 Wq->Wqt(T), z=1 Wk->Wkt(T), z=2 Wv->Wvh(RM)).
__global__ __launch_bounds__(256) void cvt_all(
    const float* __restrict__ x, const float* __restrict__ Wq,
    const float* __restrict__ Wk, const float* __restrict__ Wv,
    _Float16* __restrict__ xt, _Float16* __restrict__ xh,
    _Float16* __restrict__ Wqt, _Float16* __restrict__ Wkt,
    _Float16* __restrict__ Wvh, float* __restrict__ xs)
{
    __shared__ float tile[64][65];
    __shared__ float red[4][64];
    const int bid = blockIdx.x;
    const int t   = threadIdx.x;
    const int tr  = t >> 4;
    const int tc  = (t & 15) * 4;

    const float* src;
    _Float16 *dstT = nullptr, *dstRM = nullptr;
    int r0, c0, C, R;
    bool isX = bid < 4096;
    if (isX) {
        const int b  = bid >> 10;
        const int tt = bid & 1023;
        r0 = (tt >> 4) * 64; c0 = (tt & 15) * 64;
        R = SEQ; C = DM;
        src   = x  + (long)b * SEQ * DM;
        dstT  = xt + (long)b * SEQ * DM;
        dstRM = xh + (long)b * SEQ * DM;
        xs   += b * DM;
    } else {
        const int wb = bid - 4096;
        const int z  = wb >> 8;
        const int tt = wb & 255;
        r0 = (tt >> 4) * 64; c0 = (tt & 15) * 64;
        R = DM; C = DM;
        src = z == 0 ? Wq : (z == 1 ? Wk : Wv);
        if (z == 0) dstT = Wqt;
        else if (z == 1) dstT = Wkt;
        else dstRM = Wvh;
    }

    #pragma unroll
    for (int i = 0; i < 4; ++i) {
        const int r = tr + i * 16;
        f4 v = *(const f4*)&src[(long)(r0 + r) * C + c0 + tc];
        tile[r][tc + 0] = v.x; tile[r][tc + 1] = v.y;
        tile[r][tc + 2] = v.z; tile[r][tc + 3] = v.w;
        if (dstRM) {
            h4 h = { (_Float16)v.x, (_Float16)v.y, (_Float16)v.z, (_Float16)v.w };
            *(h4*)&dstRM[(long)(r0 + r) * C + c0 + tc] = h;
        }
    }
    __syncthreads();
    if (dstT) {
        #pragma unroll
        for (int i = 0; i < 4; ++i) {
            const int c = tr + i * 16;
            h4 h = { (_Float16)tile[tc + 0][c], (_Float16)tile[tc + 1][c],
                     (_Float16)tile[tc + 2][c], (_Float16)tile[tc + 3][c] };
            *(h4*)&dstT[(long)(c0 + c) * R + r0 + tc] = h;
        }
    }
    if (isX) {
        const int cc = t & 63;
        const int rb = (t >> 6) * 16;
        float ps = 0.f;
        #pragma unroll
        for (int r = 0; r < 16; ++r) ps += tile[rb + r][cc];
        red[t >> 6][cc] = ps;
        __syncthreads();
        if (t < 64)
            atomicAdd(&xs[c0 + t], red[0][t] + red[1][t] + red[2][t] + red[3][t]);
    }
}

// gw<4096: u2[b,e] = Wvh[e].xs[b] + S*bv[e]
// gw<5120: qk[i] = Wqt[i].bk
// gw<6144: kb[j] = Wkt[j].bq       (no atomics — sv done in reduce_tri)
__global__ __launch_bounds__(256) void gemv_misc(
    const _Float16* __restrict__ Wvh, const _Float16* __restrict__ Wqt,
    const _Float16* __restrict__ Wkt,
    const float* __restrict__ xs, const float* __restrict__ bv,
    const float* __restrict__ bk, const float* __restrict__ bq,
    float* __restrict__ u2, float* __restrict__ qk,
    float* __restrict__ kb)
{
    const int gw   = blockIdx.x * 4 + (threadIdx.x >> 6);
    const int lane = threadIdx.x & 63;
    if (gw < 4096) {
        float s = wred(doth(Wvh + (long)(gw & 1023) * DM, xs + (gw >> 10) * DM, lane));
        if (lane == 0) u2[gw] = s + (float)SEQ * bv[gw & 1023];
    } else if (gw < 5120) {
        float s = wred(doth(Wqt + (long)(gw - 4096) * DM, bk, lane));
        if (lane == 0) qk[gw - 4096] = s;
    } else {
        float s = wred(doth(Wkt + (long)(gw - 5120) * DM, bq, lane));
        if (lane == 0) kb[gw - 5120] = s;
    }
}

// gw<4096: cv[b,e] = Ph[b,e,:].kb + (sv0*u2 + sv_b*bv)/32
// else:    qw[b,i] = Mh[i,:].xs[b]
__global__ __launch_bounds__(256) void gemv_cvqw(
    const _Float16* __restrict__ Ph, const _Float16* __restrict__ Mh,
    const float* __restrict__ kb, const float* __restrict__ xs,
    const float* __restrict__ u2, const float* __restrict__ bv,
    const float* __restrict__ sv,
    float* __restrict__ cv, float* __restrict__ qw)
{
    const int gw   = blockIdx.x * 4 + (threadIdx.x >> 6);
    const int lane = threadIdx.x & 63;
    if (gw < 4096) {
        const int b = gw >> 10;
        const int e = gw & 1023;
        float s = wred(doth(Ph + (long)b * DM * DM + (long)e * DM, kb, lane));
        if (lane == 0)
            cv[gw] = s + (sv[0] * u2[gw] + sv[1 + b] * bv[e]) * 0.03125f;
    } else {
        const int g = gw - 4096;
        const int b = g >> 10;
        const int i = g & 1023;
        float s = wred(doth(Mh + (long)i * DM, xs + b * DM, lane));
        if (lane == 0) qw[g] = s;
    }
}

// Triangular reduce+mirror: Gh[b] from parts[job*6+s] (each 256x256 fp16).
// Block 640 (extra): sv[0] = bq.bk; sv[1+b] = kb.xs[b].
__global__ __launch_bounds__(256) void reduce_tri(
    const _Float16* __restrict__ parts, _Float16* __restrict__ Gh,
    const float* __restrict__ kb, const float* __restrict__ xs,
    const float* __restrict__ bq, const float* __restrict__ bk,
    float* __restrict__ sv)
{
    const int bid = blockIdx.x;
    if (bid == 640) {
        const int wv   = threadIdx.x >> 6;
        const int lane = threadIdx.x & 63;
        float s = wred(dotf(kb, xs + wv * DM, lane));
        if (lane == 0) sv[1 + wv] = s;
        if (wv == 0) {
            float s0 = wred(dotf(bq, bk, lane));
            if (lane == 0) sv[0] = s0;
        }
        return;
    }
    __shared__ _Float16 lds[64][72];
    const int job = bid >> 4;
    const int ch  = bid & 15;
    const int b   = job / 10;
    const int p   = job - b * 10;
    const int ti  = p >= 6 ? 3 : (p >= 3 ? 2 : (p >= 1 ? 1 : 0));
    const int tj  = p - ((ti * (ti + 1)) >> 1);
    const int li  = (ch >> 2) * 64;
    const int lj  = (ch & 3) * 64;
    const int t   = threadIdx.x;
    const int c8  = (t & 7) * 8;
    const long DD_ = (long)DM * DM;

    h8 o[2];
    #pragma unroll
    for (int h = 0; h < 2; ++h) {
        const int r = (t >> 3) + h * 32;
        float a[8] = {};
        #pragma unroll
        for (int s = 0; s < 6; ++s) {
            const _Float16* src = parts + ((long)(job * 6 + s) << 16);
            h8 v = *(const h8*)&src[(li + r) * 256 + lj + c8];
            #pragma unroll
            for (int j = 0; j < 8; ++j) a[j] += (float)v[j];
        }
        #pragma unroll
        for (int j = 0; j < 8; ++j) o[h][j] = (_Float16)(a[j] * 0.03125f);
        *(h8*)&Gh[b * DD_ + (long)(ti * 256 + li + r) * DM + tj * 256 + lj + c8] = o[h];
        *(h8*)&lds[r][c8] = o[h];
    }
    if (ti != tj) {
        __syncthreads();
        #pragma unroll
        for (int h = 0; h < 2; ++h) {
            const int r = (t >> 3) + h * 32;
            h8 m;
            #pragma unroll
            for (int j = 0; j < 8; ++j) m[j] = lds[c8 + j][r];
            *(h8*)&Gh[b * DD_ + (long)(tj * 256 + lj + r) * DM + ti * 256 + li + c8] = m;
        }
    }
}

// ---------------------------------------------------------------------------
// 8-phase 256x256 NT GEMM (R7/R13-frozen schedule). TRI=1: triangular Gram.
// ---------------------------------------------------------------------------
template<typename OutT, int BIAS, int TRI>
__global__ __launch_bounds__(512, 1) void gemm8p(
    const _Float16* __restrict__ A, const _Float16* __restrict__ B,
    OutT* __restrict__ C,
    int K, int lda, int ldb, int ldc, int tilesX, int perZ,
    long aZ, long bZ, long cZ, int sk, long aK, long bK,
    const float* __restrict__ bc1, long bc1Z, float alpha)
{
    __shared__ _Float16 lds[2 * 32768];   // 128 KiB

    const int L = xcd_swz(blockIdx.x, gridDim.x);
    int tileM, tileN, cTileM, cTileN, NT;
    const float* pc1 = nullptr;
    if (TRI) {
        const int job = L / 6;
        const int s   = L - job * 6;
        const int b   = job / 10;
        const int p   = job - b * 10;
        const int ti  = p >= 6 ? 3 : (p >= 3 ? 2 : (p >= 1 ? 1 : 0));
        const int tj  = p - ((ti * (ti + 1)) >> 1);
        const int kOff = s < 4 ? s * 704 : 2816 + (s - 4) * 640;
        NT = s < 4 ? 11 : 10;
        A += (long)b * aZ + kOff;
        B += (long)b * aZ + kOff;
        C += (long)(job * 6 + s) * cZ;
        tileM = ti * 256; tileN = tj * 256;
        cTileM = 0; cTileN = 0;
    } else {
        const int z  = L / perZ;
        const int r0 = L - z * perZ;
        const int zb = z / sk;
        const int zk = z - zb * sk;
        A += (long)zb * aZ + (long)zk * aK;
        B += (long)zb * bZ + (long)zk * bK;
        C += (long)z * cZ;
        if (BIAS == 1) pc1 = bc1 + (long)zb * bc1Z;
        tileM = (r0 / tilesX) * 256;
        tileN = (r0 % tilesX) * 256;
        cTileM = tileM; cTileN = tileN;
        NT = K >> 6;
    }

    const int tid  = threadIdx.x;
    const int lane = tid & 63;
    const int wave = tid >> 6;
    const int wr   = wave >> 2;
    const int wc   = wave & 3;
    const int la   = lane & 15;
    const int kg   = lane >> 4;

    auto stageA = [&](int buf, int mq, int kt) {
        _Float16* dst = &lds[buf * 32768 + mq * 8192];
        const int k0 = kt * 64;
        #pragma unroll
        for (int i = 0; i < 2; ++i) {
            const int U = i * 512 + tid;
            const int R = U >> 3, s = U & 7;
            const int gr = tileM + (R >> 6) * 128 + mq * 64 + (R & 63);
            gload_lds16(&A[(long)gr * lda + k0 + ((s ^ (R & 7)) << 3)], dst + U * 8);
        }
    };
    auto stageB = [&](int buf, int nq, int kt) {
        _Float16* dst = &lds[buf * 32768 + 16384 + nq * 8192];
        const int k0 = kt * 64;
        #pragma unroll
        for (int i = 0; i < 2; ++i) {
            const int U = i * 512 + tid;
            const int R = U >> 3, s = U & 7;
            const int gn = tileN + (R >> 5) * 64 + nq * 32 + (R & 31);
            gload_lds16(&B[(long)gn * ldb + k0 + ((s ^ (R & 7)) << 3)], dst + U * 8);
        }
    };

    f4 acc[8][4] = {};
    h8 af[4][2];
    h8 bf[2][2][2];

    auto readA = [&](int buf, int mq) {
        const _Float16* Ab = &lds[buf * 32768 + mq * 8192];
        #pragma unroll
        for (int mi = 0; mi < 4; ++mi)
            #pragma unroll
            for (int kk = 0; kk < 2; ++kk) {
                const int R = wr * 64 + mi * 16 + la;
                const int s = kk * 4 + kg;
                af[mi][kk] = *(const h8*)&Ab[R * 64 + ((s ^ (R & 7)) << 3)];
            }
    };
    auto readB = [&](int buf, int nq) {
        const _Float16* Bb = &lds[buf * 32768 + 16384 + nq * 8192];
        #pragma unroll
        for (int ni = 0; ni < 2; ++ni)
            #pragma unroll
            for (int kk = 0; kk < 2; ++kk) {
                const int R = wc * 32 + ni * 16 + la;
                const int s = kk * 4 + kg;
                bf[nq][ni][kk] = *(const h8*)&Bb[R * 64 + ((s ^ (R & 7)) << 3)];
            }
    };
    auto mfmaQ = [&](int mq, int nq) {
        __builtin_amdgcn_s_setprio(1);
        #pragma unroll
        for (int mi = 0; mi < 4; ++mi)
            #pragma unroll
            for (int ni = 0; ni < 2; ++ni)
                #pragma unroll
                for (int kk = 0; kk < 2; ++kk)
                    acc[mq * 4 + mi][nq * 2 + ni] =
                        __builtin_amdgcn_mfma_f32_16x16x32_f16(
                            af[mi][kk], bf[nq][ni][kk],
                            acc[mq * 4 + mi][nq * 2 + ni], 0, 0, 0);
        __builtin_amdgcn_s_setprio(0);
    };

    stageA(0, 0, 0); stageA(0, 1, 0); stageB(0, 0, 0); stageB(0, 1, 0);
    if (NT > 1) {
        stageA(1, 0, 1); stageB(1, 0, 1);
        asm volatile("s_waitcnt vmcnt(4)" ::: "memory");
    } else {
        asm volatile("s_waitcnt vmcnt(0)" ::: "memory");
    }
    __builtin_amdgcn_sched_barrier(0);
    __builtin_amdgcn_s_barrier();

    for (int j = 0; j < NT; ++j) {
        const int buf = j & 1;
        // P1
        readA(buf, 0); readB(buf, 0);
        if (j + 1 < NT) stageA(buf ^ 1, 1, j + 1);
        asm volatile("s_waitcnt lgkmcnt(8)" ::: "memory");
        __builtin_amdgcn_s_barrier();
        asm volatile("s_waitcnt lgkmcnt(0)" ::: "memory");
        __builtin_amdgcn_sched_barrier(0);
        mfmaQ(0, 0);
        __builtin_amdgcn_s_barrier();
        // P2
        readB(buf, 1);
        if (j + 1 < NT) stageB(buf ^ 1, 1, j + 1);
        __builtin_amdgcn_s_barrier();
        asm volatile("s_waitcnt lgkmcnt(0)" ::: "memory");
        __builtin_amdgcn_sched_barrier(0);
        mfmaQ(0, 1);
        __builtin_amdgcn_s_barrier();
        // P3
        readA(buf, 1);
        if (j + 2 < NT) stageA(buf, 0, j + 2);
        __builtin_amdgcn_s_barrier();
        asm volatile("s_waitcnt lgkmcnt(0)" ::: "memory");
        __builtin_amdgcn_sched_barrier(0);
        mfmaQ(1, 0);
        __builtin_amdgcn_s_barrier();
        // P4
        if (j + 2 < NT) stageB(buf, 0, j + 2);
        __builtin_amdgcn_s_barrier();
        mfmaQ(1, 1);
        if (j + 2 < NT) {
            asm volatile("s_waitcnt vmcnt(4)" ::: "memory");
        } else if (j + 1 < NT) {
            asm volatile("s_waitcnt vmcnt(0)" ::: "memory");
        }
        __builtin_amdgcn_sched_barrier(0);
        __builtin_amdgcn_s_barrier();
    }

    #pragma unroll
    for (int mf = 0; mf < 8; ++mf) {
        #pragma unroll
        for (int nf = 0; nf < 4; ++nf) {
            const int col = cTileN + wc * 64 + nf * 16 + la;
            #pragma unroll
            for (int jj = 0; jj < 4; ++jj) {
                const int row = cTileM + wr * 128 + mf * 16 + kg * 4 + jj;
                float v = acc[mf][nf][jj] * alpha;
                if (BIAS == 1) v += pc1[col];
                C[(long)row * ldc + col] = (OutT)v;
            }
        }
    }
}

// 64x64 NT GEMM (chain). z >= zSplit -> (A2,B2,C2), z'=0.
template<int BIAS>
__global__ __launch_bounds__(256) void gemm64(
    const _Float16* __restrict__ A, const _Float16* __restrict__ B,
    _Float16* __restrict__ C,
    const _Float16* __restrict__ A2, const _Float16* __restrict__ B2,
    _Float16* __restrict__ C2, int zSplit,
    int K, int lda, int ldb, int ldc, int tilesX, int perZ,
    long aZ, long bZ, long cZ,
    const float* __restrict__ bc1, long bc1Z,
    const float* __restrict__ br1, long br1Z,
    const float* __restrict__ bc2, long bc2Z,
    const float* __restrict__ br2, long br2Z,
    float alpha, float beta)
{
    __shared__ _Float16 As[64 * 64];
    __shared__ _Float16 Bs[64 * 64];

    const int L  = xcd_swz(blockIdx.x, gridDim.x);
    int z        = L / perZ;
    const int r0 = L - z * perZ;
    if (z >= zSplit) { A = A2; B = B2; C = C2; z = 0; }
    A += (long)z * aZ;
    B += (long)z * bZ;
    C += (long)z * cZ;
    const float* pc1 = nullptr; const float* pr1 = nullptr;
    const float* pc2 = nullptr; const float* pr2 = nullptr;
    if (BIAS == 3) {
        pc1 = bc1 + (long)z * bc1Z; pr1 = br1 + (long)z * br1Z;
        pc2 = bc2 + (long)z * bc2Z; pr2 = br2 + (long)z * br2Z;
    }

    const int tileM = (r0 / tilesX) * 64;
    const int tileN = (r0 % tilesX) * 64;
    const int tid   = threadIdx.x;
    const int lane  = tid & 63;
    const int wave  = tid >> 6;
    const int wm    = (wave >> 1) * 32;
    const int wn    = (wave & 1) * 32;
    const int srow  = tid >> 3;
    const int sslot = tid & 7;

    f4 acc[2][2] = {};
    const int arow = lane & 15;
    const int kg   = lane >> 4;

    for (int k0 = 0; k0 < K; k0 += 64) {
        #pragma unroll
        for (int i = 0; i < 2; ++i) {
            const int row   = i * 32 + srow;
            const int gslot = sslot ^ (row & 7);
            gload_lds16(&A[(long)(tileM + row) * lda + k0 + gslot * 8],
                        &As[row * 64 + sslot * 8]);
            gload_lds16(&B[(long)(tileN + row) * ldb + k0 + gslot * 8],
                        &Bs[row * 64 + sslot * 8]);
        }
        __syncthreads();

        #pragma unroll
        for (int kk = 0; kk < 64; kk += 32) {
            h8 af[2], bf[2];
            #pragma unroll
            for (int m = 0; m < 2; ++m) {
                const int rr   = wm + m * 16 + arow;
                const int slot = (kk >> 3) + kg;
                af[m] = *(const h8*)&As[rr * 64 + ((slot ^ (rr & 7)) << 3)];
            }
            #pragma unroll
            for (int n = 0; n < 2; ++n) {
                const int rr   = wn + n * 16 + arow;
                const int slot = (kk >> 3) + kg;
                bf[n] = *(const h8*)&Bs[rr * 64 + ((slot ^ (rr & 7)) << 3)];
            }
            #pragma unroll
            for (int m = 0; m < 2; ++m)
                #pragma unroll
                for (int n = 0; n < 2; ++n)
                    acc[m][n] = __builtin_amdgcn_mfma_f32_16x16x32_f16(
                        af[m], bf[n], acc[m][n], 0, 0, 0);
        }
        __syncthreads();
    }

    #pragma unroll
    for (int m = 0; m < 2; ++m) {
        #pragma unroll
        for (int n = 0; n < 2; ++n) {
            const int col = tileN + wn + n * 16 + arow;
            #pragma unroll
            for (int j = 0; j < 4; ++j) {
                const int row = tileM + wm + m * 16 + (lane >> 4) * 4 + j;
                float v = acc[m][n][j] * alpha;
                if (BIAS == 3) v += beta * (pc1[col] * pr1[row] + pc2[col] * pr2[row]);
                C[(long)row * ldc + col] = (_Float16)v;
            }
        }
    }
}

extern "C" void kernel_launch(void* const* d_in, const int* in_sizes, int n_in,
                              void* d_out, int out_size, void* d_ws, size_t ws_size,
                              hipStream_t stream)
{
    const float* x  = (const float*)d_in[0];
    const float* Wq = (const float*)d_in[1];
    const float* bq = (const float*)d_in[2];
    const float* Wk = (const float*)d_in[3];
    const float* bk = (const float*)d_in[4];
    const float* Wv = (const float*)d_in[5];
    const float* bv = (const float*)d_in[6];
    float* out = (float*)d_out;

    const long DD = (long)DM * DM;
    const long DS = (long)DM * SEQ;
    const long MB = 1024l * 1024;

    char* base = (char*)d_ws;
    _Float16* xh   = (_Float16*)base;
    _Float16* xt   = (_Float16*)(base + 32 * MB);
    _Float16* Gh   = xt;                                  // reuse after xt dead
    _Float16* Ph   = (_Float16*)(base + 40 * MB);
    _Float16* Rth  = (_Float16*)(base + 48 * MB);
    _Float16* Wqt  = (_Float16*)(base + 64 * MB);
    _Float16* Wvh  = (_Float16*)(base + 66 * MB);
    _Float16* Wkt  = (_Float16*)(base + 68 * MB);
    _Float16* Mh   = (_Float16*)(base + 70 * MB);
    float*    vecs = (float*)(base + 72 * MB);
    float*    u2   = vecs;                // 4096
    float*    qk   = vecs + 4096;         // 1024
    float*    kb   = vecs + 5120;         // 1024
    float*    xs   = vecs + 6144;         // 4096
    float*    qw   = vecs + 10240;        // 4096
    float*    cv   = vecs + 14336;        // 4096
    float*    sv   = vecs + 18432;        // 8
    _Float16* parts = (_Float16*)d_out;   // 240 x 256^2 fp16 = 30MB scratch

    // 0) zero xs (atomically accumulated by cvt_all)
    hipMemsetAsync(xs, 0, BATCH * DM * sizeof(float), stream);

    // 1) all converts + fused col-sums (x: 4096 blocks, weights: 768)
    cvt_all<<<4864, 256, 0, stream>>>(x, Wq, Wk, Wv, xt, xh, Wqt, Wkt, Wvh, xs);

    // 2) u2, qk, kb  (no atomics)
    gemv_misc<<<1536, 256, 0, stream>>>(Wvh, Wqt, Wkt, xs, bv, bk, bq, u2, qk, kb);

    // 3) Triangular Gram: parts[job*6+s] = lower-tri 256^2 tile, K-slice s
    gemm8p<_Float16, 0, 1><<<240, 512, 0, stream>>>(
        xt, xt, parts, 4096, SEQ, SEQ, 256, 0, 0,
        DS, DS, 65536, 1, 0, 0, nullptr, 0, 1.0f);

    // 4) Gh = (1/32)*sum_s parts, mirrored (+ block 640: sv)
    reduce_tri<<<641, 256, 0, stream>>>(parts, Gh, kb, xs, bq, bk, sv);

    // 5) Ph[b] = Wv.Gh[b] (z<4)  ||  Mh = Wqt.Wkt^T (z=4)
    gemm64<0><<<1280, 256, 0, stream>>>(
        Wvh, Gh, Ph, Wqt, Wkt, Mh, 4,
        1024, DM, DM, DM, 16, 256,
        0, DD, DD,
        nullptr, 0, nullptr, 0, nullptr, 0, nullptr, 0, 1.0f, 0.f);

    // 6) cv (from Ph,kb,sv) + qw (= Mh.xs)
    gemv_cvqw<<<2048, 256, 0, stream>>>(Ph, Mh, kb, xs, u2, bv, sv, cv, qw);

    // 7) Rt[b] = Ph.M^T + (1/32)(qk ox u2 + qw ox bv)
    gemm64<3><<<1024, 256, 0, stream>>>(
        Ph, Mh, Rth, nullptr, nullptr, nullptr, 99,
        1024, DM, DM, DM, 16, 256,
        DD, 0, DD,
        qk, 0, u2, 1024, qw, 1024, bv, 0, 1.0f, 0.03125f);

    // 8) E[b] = xh.Rt^T + cv -> fp32 out
    gemm8p<float, 1, 0><<<256, 512, 0, stream>>>(
        xh, Rth, out, 1024, DM, DM, DM, 4, 64,
        DS, DD, DS, 1, 0, 0, cv, 1024, 1.0f);
}